// Round 1
// 533.258 us; speedup vs baseline: 1.1385x; 1.1385x over previous
//
#include <hip/hip_runtime.h>
#include <math.h>

#define BB 8
#define CC 64
#define HH 256
#define WW 256
#define NN (HH*WW)          // 65536
#define LDS_STRIDE 68       // 272 B rows: 16B-aligned
#define JCHUNK 4            // j rows accumulated per block

typedef float v4f __attribute__((ext_vector_type(4)));   // native vec for NT stores

// ---------------------------------------------------------------------------
// Stage 1: corr[b,p,q] = sum_{j,i} X[b,p,j,i] * Y[b,q,j,i]
//          Y[b,q,j,i] = w0(i)*X[b,q,j,k0(i)] + w1(i)*X[b,q,j,k1(i)]
// One block per (j-chunk of 4 rows, batch b). 512 threads = 8 waves.
// Each wave covers the FULL 64x64 output with an 8x8 tile per lane and a
// 32-i slice per row; acc lives in registers across the 4 rows; 8 wave
// partials are tree-reduced in LDS, then one atomic set per block.
// ---------------------------------------------------------------------------
__global__ __launch_bounds__(512, 4)
void corr_kernel(const float* __restrict__ x, const int* __restrict__ angle_p,
                 float* __restrict__ corr) {
    __shared__ float  Xs[WW][LDS_STRIDE];   // 69632 B (also reduction scratch)
    __shared__ float4 tbl[WW];              // 4096 B

    const int jc  = blockIdx.x;   // j-chunk 0..63
    const int b   = blockIdx.y;   // batch 0..7
    const int tid = threadIdx.x;  // 0..511

    // --- per-i table, exactly mirroring the reference fp32 math (j-independent)
    if (tid < 256) {
        const double a  = (double)(*angle_p);
        const float  cf = (float)cos(a);
        const float  sf = (float)sin(a);
        const int i = tid;
        const float gx    = (2.0f * (float)i + 1.0f) / 256.0f - 1.0f; // exact
        const float gridx = cf * gx;
        const float gridz = (-sf) * gx;
        const float ix = ((gridx + 1.0f) * 256.0f - 1.0f) * 0.5f;
        const float t1 = (gridz + 1.0f);        // *D with D=1
        const float iz = (t1 - 1.0f) * 0.5f;
        const float ix0f = floorf(ix), iz0f = floorf(iz);
        const float fx = ix - ix0f,    fz = iz - iz0f;
        const int   ix0 = (int)ix0f,   iz0 = (int)iz0f;
        float wz = 0.0f;
        if (iz0 ==  0) wz += 1.0f - fz;   // dz=0 corner valid (zi=0)
        if (iz0 == -1) wz += fz;          // dz=1 corner valid (zi=0)
        float w0 = (1.0f - fx) * wz;
        float w1 = fx * wz;
        int k0 = ix0, k1 = ix0 + 1;
        if (k0 < 0 || k0 >= WW) { w0 = 0.0f; k0 = 0; }   // zeros padding
        if (k1 < 0 || k1 >= WW) { w1 = 0.0f; k1 = 0; }
        tbl[i] = make_float4(w0, w1, __int_as_float(k0), __int_as_float(k1));
    }

    const int w    = tid >> 6;    // wave 0..7 -> i slice [32w, 32w+32)
    const int lane = tid & 63;
    const int lr   = lane >> 3;   // p-group (8 rows  at 8*lr)
    const int lc   = lane & 7;    // q-group (8 cols  at 8*lc)

    float4 acc0[8], acc1[8];      // [r]: cols 8lc..+3 / 8lc+4..+7
    #pragma unroll
    for (int r = 0; r < 8; ++r) {
        acc0[r] = make_float4(0.f, 0.f, 0.f, 0.f);
        acc1[r] = make_float4(0.f, 0.f, 0.f, 0.f);
    }

    const int si = tid & 255;         // staging: i index
    const int c0 = (tid >> 8) * 32;   // staging: channel base (0 or 32)

    for (int jj = 0; jj < JCHUNK; ++jj) {
        const int j = jc * JCHUNK + jj;
        __syncthreads();   // prior compute (and tbl write on first pass) done
        // --- load row j of all 64 channels into LDS (i-major, channel contiguous)
        {
            const float* xb = x + (size_t)(b * CC) * NN + (size_t)j * WW;
            #pragma unroll 8
            for (int cc = 0; cc < 32; ++cc)
                Xs[si][c0 + cc] = xb[(size_t)(c0 + cc) * NN + si];
        }
        __syncthreads();

        // --- 32 i's per wave; 7 LDS reads -> 64 FMAs per i
        const int ib = 32 * w;
        float4 tv = tbl[ib];
        for (int ii = 0; ii < 32; ++ii) {
            const int i = ib + ii;
            const float4 tn = tbl[(i + 1) & 255];   // 1-ahead prefetch
            const int   k0 = __float_as_int(tv.z);
            const int   k1 = __float_as_int(tv.w);
            const float w0 = tv.x, w1 = tv.y;

            const float4 xpa = *(const float4*)&Xs[i][8 * lr];
            const float4 xpb = *(const float4*)&Xs[i][8 * lr + 4];
            const float4 a0  = *(const float4*)&Xs[k0][8 * lc];
            const float4 a1  = *(const float4*)&Xs[k0][8 * lc + 4];
            const float4 b0  = *(const float4*)&Xs[k1][8 * lc];
            const float4 b1  = *(const float4*)&Xs[k1][8 * lc + 4];

            float4 y0, y1;
            y0.x = fmaf(w1, b0.x, w0 * a0.x);
            y0.y = fmaf(w1, b0.y, w0 * a0.y);
            y0.z = fmaf(w1, b0.z, w0 * a0.z);
            y0.w = fmaf(w1, b0.w, w0 * a0.w);
            y1.x = fmaf(w1, b1.x, w0 * a1.x);
            y1.y = fmaf(w1, b1.y, w0 * a1.y);
            y1.z = fmaf(w1, b1.z, w0 * a1.z);
            y1.w = fmaf(w1, b1.w, w0 * a1.w);

            const float xp[8] = {xpa.x, xpa.y, xpa.z, xpa.w,
                                 xpb.x, xpb.y, xpb.z, xpb.w};
            #pragma unroll
            for (int r = 0; r < 8; ++r) {
                acc0[r].x = fmaf(xp[r], y0.x, acc0[r].x);
                acc0[r].y = fmaf(xp[r], y0.y, acc0[r].y);
                acc0[r].z = fmaf(xp[r], y0.z, acc0[r].z);
                acc0[r].w = fmaf(xp[r], y0.w, acc0[r].w);
                acc1[r].x = fmaf(xp[r], y1.x, acc1[r].x);
                acc1[r].y = fmaf(xp[r], y1.y, acc1[r].y);
                acc1[r].z = fmaf(xp[r], y1.z, acc1[r].z);
                acc1[r].w = fmaf(xp[r], y1.w, acc1[r].w);
            }
            tv = tn;
        }
    }

    // --- cross-wave tree reduction in LDS (reuse Xs: 4 slots x 16 KB)
    float4* S4 = (float4*)&Xs[0][0];
    const int idx0 = (8 * lr) * 16 + 2 * lc;   // float4 index; per-r: +16*r

    __syncthreads();
    if (w >= 4) {
        float4* dst = S4 + (size_t)(w - 4) * 1024;
        #pragma unroll
        for (int r = 0; r < 8; ++r) {
            dst[idx0 + 16 * r]     = acc0[r];
            dst[idx0 + 16 * r + 1] = acc1[r];
        }
    }
    __syncthreads();
    if (w < 4) {
        const float4* src = S4 + (size_t)w * 1024;
        #pragma unroll
        for (int r = 0; r < 8; ++r) {
            const float4 u = src[idx0 + 16 * r];
            const float4 v = src[idx0 + 16 * r + 1];
            acc0[r].x += u.x; acc0[r].y += u.y; acc0[r].z += u.z; acc0[r].w += u.w;
            acc1[r].x += v.x; acc1[r].y += v.y; acc1[r].z += v.z; acc1[r].w += v.w;
        }
    }
    __syncthreads();
    if (w == 2 || w == 3) {
        float4* dst = S4 + (size_t)(w - 2) * 1024;
        #pragma unroll
        for (int r = 0; r < 8; ++r) {
            dst[idx0 + 16 * r]     = acc0[r];
            dst[idx0 + 16 * r + 1] = acc1[r];
        }
    }
    __syncthreads();
    if (w < 2) {
        const float4* src = S4 + (size_t)w * 1024;
        #pragma unroll
        for (int r = 0; r < 8; ++r) {
            const float4 u = src[idx0 + 16 * r];
            const float4 v = src[idx0 + 16 * r + 1];
            acc0[r].x += u.x; acc0[r].y += u.y; acc0[r].z += u.z; acc0[r].w += u.w;
            acc1[r].x += v.x; acc1[r].y += v.y; acc1[r].z += v.z; acc1[r].w += v.w;
        }
    }
    __syncthreads();
    if (w == 1) {
        #pragma unroll
        for (int r = 0; r < 8; ++r) {
            S4[idx0 + 16 * r]     = acc0[r];
            S4[idx0 + 16 * r + 1] = acc1[r];
        }
    }
    __syncthreads();
    if (w == 0) {
        #pragma unroll
        for (int r = 0; r < 8; ++r) {
            const float4 u = S4[idx0 + 16 * r];
            const float4 v = S4[idx0 + 16 * r + 1];
            acc0[r].x += u.x; acc0[r].y += u.y; acc0[r].z += u.z; acc0[r].w += u.w;
            acc1[r].x += v.x; acc1[r].y += v.y; acc1[r].z += v.z; acc1[r].w += v.w;
        }
        float* cb = corr + (size_t)b * CC * CC;
        #pragma unroll
        for (int r = 0; r < 8; ++r) {
            const int off = (8 * lr + r) * CC + 8 * lc;
            atomicAdd(&cb[off + 0], acc0[r].x);
            atomicAdd(&cb[off + 1], acc0[r].y);
            atomicAdd(&cb[off + 2], acc0[r].z);
            atomicAdd(&cb[off + 3], acc0[r].w);
            atomicAdd(&cb[off + 4], acc1[r].x);
            atomicAdd(&cb[off + 5], acc1[r].y);
            atomicAdd(&cb[off + 6], acc1[r].z);
            atomicAdd(&cb[off + 7], acc1[r].w);
        }
    }
}

// ---------------------------------------------------------------------------
// Stage 2: softmax over dim=1 (rows i) per column j; store transposed:
//          proT[b][j][i] = softmax_i(corr[b,:,j])[i]
// ---------------------------------------------------------------------------
__global__ void softmax_kernel(const float* __restrict__ corr,
                               float* __restrict__ proT) {
    const int b  = blockIdx.x;
    const int jj = threadIdx.x;   // column j, 0..63
    const float* cb = corr + (size_t)b * CC * CC;
    float v[CC];
    float m = -1e30f;
    #pragma unroll
    for (int i = 0; i < CC; ++i) {
        v[i] = cb[i * CC + jj];
        m = fmaxf(m, v[i]);
    }
    float ssum = 0.0f;
    #pragma unroll
    for (int i = 0; i < CC; ++i) {
        v[i] = expf(v[i] - m);
        ssum += v[i];
    }
    const float inv = 1.0f / ssum;
    float* pb = proT + (size_t)b * CC * CC + (size_t)jj * CC;
    #pragma unroll
    for (int i = 0; i < CC; ++i) pb[i] = v[i] * inv;
}

// ---------------------------------------------------------------------------
// Stage 3: out[b,p,n] = sum_q pro[b,p,q] * x[b,q,n]
// One block per (b, 256-col chunk). 4-deep load pipeline; NT stores.
// #pragma unroll 4 on the q loop keeps buf[] statically indexed (registers,
// not scratch — rule #20).
// ---------------------------------------------------------------------------
__global__ __launch_bounds__(256, 4)
void apply_kernel(const float* __restrict__ x, const float* __restrict__ proT,
                  float* __restrict__ out) {
    __shared__ float P[CC * CC];   // P[q*64 + p] = pro[p][q]
    const int b   = blockIdx.y;
    const int n0  = blockIdx.x * 256;
    const int tid = threadIdx.x;
    for (int t = tid; t < CC * CC; t += 256)
        P[t] = proT[(size_t)b * CC * CC + t];
    __syncthreads();

    const int lane = tid & 63;
    const int pg   = tid >> 6;     // wave index == p-group (16 p's each)
    const float* xb = x + (size_t)b * CC * NN + n0 + 4 * lane;

    float4 acc[16];
    #pragma unroll
    for (int r = 0; r < 16; ++r) acc[r] = make_float4(0.f, 0.f, 0.f, 0.f);

    // 4-deep prefetch pipeline: 4 KB in flight per wave
    float4 buf[4];
    #pragma unroll
    for (int u = 0; u < 4; ++u) buf[u] = *(const float4*)(xb + (size_t)u * NN);

    #pragma unroll 4
    for (int q = 0; q < CC; ++q) {
        const float4 xv = buf[q & 3];
        if (q + 4 < CC) buf[q & 3] = *(const float4*)(xb + (size_t)(q + 4) * NN);

        const float4* pr4 = (const float4*)&P[q * CC + pg * 16];
        const float4 pa = pr4[0], pbv = pr4[1], pc = pr4[2], pd = pr4[3];
        const float pv[16] = {pa.x, pa.y, pa.z, pa.w, pbv.x, pbv.y, pbv.z, pbv.w,
                              pc.x, pc.y, pc.z, pc.w, pd.x, pd.y, pd.z, pd.w};
        #pragma unroll
        for (int r = 0; r < 16; ++r) {
            acc[r].x = fmaf(pv[r], xv.x, acc[r].x);
            acc[r].y = fmaf(pv[r], xv.y, acc[r].y);
            acc[r].z = fmaf(pv[r], xv.z, acc[r].z);
            acc[r].w = fmaf(pv[r], xv.w, acc[r].w);
        }
    }

    float* ob = out + (size_t)b * CC * NN + n0 + 4 * lane;
    #pragma unroll
    for (int r = 0; r < 16; ++r) {
        v4f v = {acc[r].x, acc[r].y, acc[r].z, acc[r].w};
        __builtin_nontemporal_store(v, (v4f*)(ob + (size_t)(pg * 16 + r) * NN));
    }
}

// ---------------------------------------------------------------------------
extern "C" void kernel_launch(void* const* d_in, const int* in_sizes, int n_in,
                              void* d_out, int out_size, void* d_ws, size_t ws_size,
                              hipStream_t stream) {
    const float* x     = (const float*)d_in[0];
    const int*   angle = (const int*)d_in[1];
    float*       out   = (float*)d_out;

    float* corr = (float*)d_ws;                  // [8][64][64]
    float* proT = corr + (size_t)BB * CC * CC;   // [8][64(j)][64(i)]

    (void)hipMemsetAsync(d_ws, 0, (size_t)BB * CC * CC * sizeof(float), stream);

    corr_kernel<<<dim3(HH / JCHUNK, BB), 512, 0, stream>>>(x, angle, corr);
    softmax_kernel<<<dim3(BB), dim3(CC), 0, stream>>>(corr, proT);
    apply_kernel<<<dim3(NN / 256, BB), 256, 0, stream>>>(x, proT, out);
}

// Round 2
// 439.780 us; speedup vs baseline: 1.3805x; 1.2126x over previous
//
#include <hip/hip_runtime.h>
#include <math.h>

#define BB 8
#define CC 64
#define HH 256
#define WW 256
#define NN (HH*WW)          // 65536
#define LDS_STRIDE 68       // 272 B rows: 16B-aligned
#define JCHUNK 4            // j rows accumulated per block

// ---------------------------------------------------------------------------
// Stage 1: corr[b,p,q] = sum_{j,i} X[b,p,j,i] * Y[b,q,j,i]
//          Y[b,q,j,i] = w0(i)*X[b,q,j,k0(i)] + w1(i)*X[b,q,j,k1(i)]
// One block per (j-chunk of 4 rows, batch b). 512 threads = 8 waves.
// Each wave covers the FULL 64x64 output with an 8x8 tile per lane and a
// 32-i slice per row; acc lives in registers across the 4 rows; 8 wave
// partials are tree-reduced in LDS, then one atomic set per block.
// ---------------------------------------------------------------------------
__global__ __launch_bounds__(512, 4)
void corr_kernel(const float* __restrict__ x, const int* __restrict__ angle_p,
                 float* __restrict__ corr) {
    __shared__ float  Xs[WW][LDS_STRIDE];   // 69632 B (also reduction scratch)
    __shared__ float4 tbl[WW];              // 4096 B

    const int jc  = blockIdx.x;   // j-chunk 0..63
    const int b   = blockIdx.y;   // batch 0..7
    const int tid = threadIdx.x;  // 0..511

    // --- per-i table, exactly mirroring the reference fp32 math (j-independent)
    if (tid < 256) {
        const double a  = (double)(*angle_p);
        const float  cf = (float)cos(a);
        const float  sf = (float)sin(a);
        const int i = tid;
        const float gx    = (2.0f * (float)i + 1.0f) / 256.0f - 1.0f; // exact
        const float gridx = cf * gx;
        const float gridz = (-sf) * gx;
        const float ix = ((gridx + 1.0f) * 256.0f - 1.0f) * 0.5f;
        const float t1 = (gridz + 1.0f);        // *D with D=1
        const float iz = (t1 - 1.0f) * 0.5f;
        const float ix0f = floorf(ix), iz0f = floorf(iz);
        const float fx = ix - ix0f,    fz = iz - iz0f;
        const int   ix0 = (int)ix0f,   iz0 = (int)iz0f;
        float wz = 0.0f;
        if (iz0 ==  0) wz += 1.0f - fz;   // dz=0 corner valid (zi=0)
        if (iz0 == -1) wz += fz;          // dz=1 corner valid (zi=0)
        float w0 = (1.0f - fx) * wz;
        float w1 = fx * wz;
        int k0 = ix0, k1 = ix0 + 1;
        if (k0 < 0 || k0 >= WW) { w0 = 0.0f; k0 = 0; }   // zeros padding
        if (k1 < 0 || k1 >= WW) { w1 = 0.0f; k1 = 0; }
        tbl[i] = make_float4(w0, w1, __int_as_float(k0), __int_as_float(k1));
    }

    const int w    = tid >> 6;    // wave 0..7 -> i slice [32w, 32w+32)
    const int lane = tid & 63;
    const int lr   = lane >> 3;   // p-group (8 rows  at 8*lr)
    const int lc   = lane & 7;    // q-group (8 cols  at 8*lc)

    float4 acc0[8], acc1[8];      // [r]: cols 8lc..+3 / 8lc+4..+7
    #pragma unroll
    for (int r = 0; r < 8; ++r) {
        acc0[r] = make_float4(0.f, 0.f, 0.f, 0.f);
        acc1[r] = make_float4(0.f, 0.f, 0.f, 0.f);
    }

    const int si = tid & 255;         // staging: i index
    const int c0 = (tid >> 8) * 32;   // staging: channel base (0 or 32)

    for (int jj = 0; jj < JCHUNK; ++jj) {
        const int j = jc * JCHUNK + jj;
        __syncthreads();   // prior compute (and tbl write on first pass) done
        // --- load row j of all 64 channels into LDS (i-major, channel contiguous)
        // unroll 16: two latency batches instead of four (32 independent
        // 4B strided loads; deeper issue window hides ~600cy L2/L3 latency)
        {
            const float* xb = x + (size_t)(b * CC) * NN + (size_t)j * WW;
            #pragma unroll 16
            for (int cc = 0; cc < 32; ++cc)
                Xs[si][c0 + cc] = xb[(size_t)(c0 + cc) * NN + si];
        }
        __syncthreads();

        // --- 32 i's per wave; 7 LDS reads -> 64 FMAs per i
        const int ib = 32 * w;
        float4 tv = tbl[ib];
        for (int ii = 0; ii < 32; ++ii) {
            const int i = ib + ii;
            const float4 tn = tbl[(i + 1) & 255];   // 1-ahead prefetch
            const int   k0 = __float_as_int(tv.z);
            const int   k1 = __float_as_int(tv.w);
            const float w0 = tv.x, w1 = tv.y;

            const float4 xpa = *(const float4*)&Xs[i][8 * lr];
            const float4 xpb = *(const float4*)&Xs[i][8 * lr + 4];
            const float4 a0  = *(const float4*)&Xs[k0][8 * lc];
            const float4 a1  = *(const float4*)&Xs[k0][8 * lc + 4];
            const float4 b0  = *(const float4*)&Xs[k1][8 * lc];
            const float4 b1  = *(const float4*)&Xs[k1][8 * lc + 4];

            float4 y0, y1;
            y0.x = fmaf(w1, b0.x, w0 * a0.x);
            y0.y = fmaf(w1, b0.y, w0 * a0.y);
            y0.z = fmaf(w1, b0.z, w0 * a0.z);
            y0.w = fmaf(w1, b0.w, w0 * a0.w);
            y1.x = fmaf(w1, b1.x, w0 * a1.x);
            y1.y = fmaf(w1, b1.y, w0 * a1.y);
            y1.z = fmaf(w1, b1.z, w0 * a1.z);
            y1.w = fmaf(w1, b1.w, w0 * a1.w);

            const float xp[8] = {xpa.x, xpa.y, xpa.z, xpa.w,
                                 xpb.x, xpb.y, xpb.z, xpb.w};
            #pragma unroll
            for (int r = 0; r < 8; ++r) {
                acc0[r].x = fmaf(xp[r], y0.x, acc0[r].x);
                acc0[r].y = fmaf(xp[r], y0.y, acc0[r].y);
                acc0[r].z = fmaf(xp[r], y0.z, acc0[r].z);
                acc0[r].w = fmaf(xp[r], y0.w, acc0[r].w);
                acc1[r].x = fmaf(xp[r], y1.x, acc1[r].x);
                acc1[r].y = fmaf(xp[r], y1.y, acc1[r].y);
                acc1[r].z = fmaf(xp[r], y1.z, acc1[r].z);
                acc1[r].w = fmaf(xp[r], y1.w, acc1[r].w);
            }
            tv = tn;
        }
    }

    // --- cross-wave tree reduction in LDS (reuse Xs: 4 slots x 16 KB)
    float4* S4 = (float4*)&Xs[0][0];
    const int idx0 = (8 * lr) * 16 + 2 * lc;   // float4 index; per-r: +16*r

    __syncthreads();
    if (w >= 4) {
        float4* dst = S4 + (size_t)(w - 4) * 1024;
        #pragma unroll
        for (int r = 0; r < 8; ++r) {
            dst[idx0 + 16 * r]     = acc0[r];
            dst[idx0 + 16 * r + 1] = acc1[r];
        }
    }
    __syncthreads();
    if (w < 4) {
        const float4* src = S4 + (size_t)w * 1024;
        #pragma unroll
        for (int r = 0; r < 8; ++r) {
            const float4 u = src[idx0 + 16 * r];
            const float4 v = src[idx0 + 16 * r + 1];
            acc0[r].x += u.x; acc0[r].y += u.y; acc0[r].z += u.z; acc0[r].w += u.w;
            acc1[r].x += v.x; acc1[r].y += v.y; acc1[r].z += v.z; acc1[r].w += v.w;
        }
    }
    __syncthreads();
    if (w == 2 || w == 3) {
        float4* dst = S4 + (size_t)(w - 2) * 1024;
        #pragma unroll
        for (int r = 0; r < 8; ++r) {
            dst[idx0 + 16 * r]     = acc0[r];
            dst[idx0 + 16 * r + 1] = acc1[r];
        }
    }
    __syncthreads();
    if (w < 2) {
        const float4* src = S4 + (size_t)w * 1024;
        #pragma unroll
        for (int r = 0; r < 8; ++r) {
            const float4 u = src[idx0 + 16 * r];
            const float4 v = src[idx0 + 16 * r + 1];
            acc0[r].x += u.x; acc0[r].y += u.y; acc0[r].z += u.z; acc0[r].w += u.w;
            acc1[r].x += v.x; acc1[r].y += v.y; acc1[r].z += v.z; acc1[r].w += v.w;
        }
    }
    __syncthreads();
    if (w == 1) {
        #pragma unroll
        for (int r = 0; r < 8; ++r) {
            S4[idx0 + 16 * r]     = acc0[r];
            S4[idx0 + 16 * r + 1] = acc1[r];
        }
    }
    __syncthreads();
    if (w == 0) {
        #pragma unroll
        for (int r = 0; r < 8; ++r) {
            const float4 u = S4[idx0 + 16 * r];
            const float4 v = S4[idx0 + 16 * r + 1];
            acc0[r].x += u.x; acc0[r].y += u.y; acc0[r].z += u.z; acc0[r].w += u.w;
            acc1[r].x += v.x; acc1[r].y += v.y; acc1[r].z += v.z; acc1[r].w += v.w;
        }
        float* cb = corr + (size_t)b * CC * CC;
        #pragma unroll
        for (int r = 0; r < 8; ++r) {
            const int off = (8 * lr + r) * CC + 8 * lc;
            atomicAdd(&cb[off + 0], acc0[r].x);
            atomicAdd(&cb[off + 1], acc0[r].y);
            atomicAdd(&cb[off + 2], acc0[r].z);
            atomicAdd(&cb[off + 3], acc0[r].w);
            atomicAdd(&cb[off + 4], acc1[r].x);
            atomicAdd(&cb[off + 5], acc1[r].y);
            atomicAdd(&cb[off + 6], acc1[r].z);
            atomicAdd(&cb[off + 7], acc1[r].w);
        }
    }
}

// ---------------------------------------------------------------------------
// Stage 2: softmax over dim=1 (rows i) per column j; store transposed:
//          proT[b][j][i] = softmax_i(corr[b,:,j])[i]
// ---------------------------------------------------------------------------
__global__ void softmax_kernel(const float* __restrict__ corr,
                               float* __restrict__ proT) {
    const int b  = blockIdx.x;
    const int jj = threadIdx.x;   // column j, 0..63
    const float* cb = corr + (size_t)b * CC * CC;
    float v[CC];
    float m = -1e30f;
    #pragma unroll
    for (int i = 0; i < CC; ++i) {
        v[i] = cb[i * CC + jj];
        m = fmaxf(m, v[i]);
    }
    float ssum = 0.0f;
    #pragma unroll
    for (int i = 0; i < CC; ++i) {
        v[i] = expf(v[i] - m);
        ssum += v[i];
    }
    const float inv = 1.0f / ssum;
    float* pb = proT + (size_t)b * CC * CC + (size_t)jj * CC;
    #pragma unroll
    for (int i = 0; i < CC; ++i) pb[i] = v[i] * inv;
}

// ---------------------------------------------------------------------------
// Stage 3: out[b,p,n] = sum_q pro[b,p,q] * x[b,q,n]
// One block per (b, 256-col chunk). 512 threads = 8 waves; each wave owns
// 8 p-rows (acc[8]x float4 = 32 VGPRs -> ~5 waves/SIMD vs old 4).
// Plain float4 stores (NT stores showed 6x WRITE_SIZE amplification).
// 4-deep statically-indexed prefetch pipeline (rule #20 safe via unroll 4).
// ---------------------------------------------------------------------------
__global__ __launch_bounds__(512, 4)
void apply_kernel(const float* __restrict__ x, const float* __restrict__ proT,
                  float* __restrict__ out) {
    __shared__ float P[CC * CC];   // P[q*64 + p] = pro[p][q]
    const int b   = blockIdx.y;
    const int n0  = blockIdx.x * 256;
    const int tid = threadIdx.x;
    for (int t = tid; t < CC * CC; t += 512)
        P[t] = proT[(size_t)b * CC * CC + t];
    __syncthreads();

    const int lane = tid & 63;
    const int w    = tid >> 6;     // wave index == p-group (8 p's each)
    const float* xb = x + (size_t)b * CC * NN + n0 + 4 * lane;

    float4 acc[8];
    #pragma unroll
    for (int r = 0; r < 8; ++r) acc[r] = make_float4(0.f, 0.f, 0.f, 0.f);

    // 4-deep prefetch pipeline: 4 KB in flight per wave
    float4 buf[4];
    #pragma unroll
    for (int u = 0; u < 4; ++u) buf[u] = *(const float4*)(xb + (size_t)u * NN);

    #pragma unroll 4
    for (int q = 0; q < CC; ++q) {
        const float4 xv = buf[q & 3];
        if (q + 4 < CC) buf[q & 3] = *(const float4*)(xb + (size_t)(q + 4) * NN);

        const float4 pa = *(const float4*)&P[q * CC + 8 * w];
        const float4 pb = *(const float4*)&P[q * CC + 8 * w + 4];
        const float pv[8] = {pa.x, pa.y, pa.z, pa.w, pb.x, pb.y, pb.z, pb.w};
        #pragma unroll
        for (int r = 0; r < 8; ++r) {
            acc[r].x = fmaf(pv[r], xv.x, acc[r].x);
            acc[r].y = fmaf(pv[r], xv.y, acc[r].y);
            acc[r].z = fmaf(pv[r], xv.z, acc[r].z);
            acc[r].w = fmaf(pv[r], xv.w, acc[r].w);
        }
    }

    float* ob = out + (size_t)b * CC * NN + n0 + 4 * lane;
    #pragma unroll
    for (int r = 0; r < 8; ++r) {
        *(float4*)(ob + (size_t)(8 * w + r) * NN) = acc[r];
    }
}

// ---------------------------------------------------------------------------
extern "C" void kernel_launch(void* const* d_in, const int* in_sizes, int n_in,
                              void* d_out, int out_size, void* d_ws, size_t ws_size,
                              hipStream_t stream) {
    const float* x     = (const float*)d_in[0];
    const int*   angle = (const int*)d_in[1];
    float*       out   = (float*)d_out;

    float* corr = (float*)d_ws;                  // [8][64][64]
    float* proT = corr + (size_t)BB * CC * CC;   // [8][64(j)][64(i)]

    (void)hipMemsetAsync(d_ws, 0, (size_t)BB * CC * CC * sizeof(float), stream);

    corr_kernel<<<dim3(HH / JCHUNK, BB), 512, 0, stream>>>(x, angle, corr);
    softmax_kernel<<<dim3(BB), dim3(CC), 0, stream>>>(corr, proT);
    apply_kernel<<<dim3(NN / 256, BB), 512, 0, stream>>>(x, proT, out);
}

// Round 4
// 364.574 us; speedup vs baseline: 1.6653x; 1.2063x over previous
//
#include <hip/hip_runtime.h>
#include <math.h>

#define BB 8
#define CC 64
#define HH 256
#define WW 256
#define NN (HH*WW)          // 65536
#define LDS_STRIDE 68       // 272 B rows: 16B-aligned
#define JCHUNK 8            // j rows accumulated per block -> 32x8 = 256 blocks = 1/CU

// channel -> LDS word column, interleaved so every float4 read set
// {col4 = g} / {col4 = g+8} (g=0..7) spans all 32 banks exactly once.
// cb = c>>2 (channel block); col4 = (cb>>1) | ((cb&1)<<3); word = col4*4 + (c&3)
__device__ __forceinline__ int colw(int c) {
    const int cb = c >> 2;
    const int col4 = (cb >> 1) | ((cb & 1) << 3);
    return col4 * 4 + (c & 3);
}

__device__ __forceinline__ float rlf(float v, int l) {
    return __int_as_float(__builtin_amdgcn_readlane(__float_as_int(v), l));
}

// ---------------------------------------------------------------------------
// Stage 1: corr[b,p,q] = sum_{j,i} X[b,p,j,i] * Y[b,q,j,i]
//          Y[b,q,j,i] = w0(i)*X[b,q,j,k0(i)] + w1(i)*X[b,q,j,k1(i)]
// One block per (j-chunk of 8 rows, batch b) -> 256 blocks = 1/CU (136 KiB LDS).
// Double-buffered row staging: loads for j+2 issued during compute of j,
// ds_writes land in the idle buffer. Channel-interleaved LDS layout makes all
// LDS traffic bank-conflict-free. tbl lives in registers (readlane per i).
// ---------------------------------------------------------------------------
__global__ __launch_bounds__(512, 2)
void corr_kernel(const float* __restrict__ x, const int* __restrict__ angle_p,
                 float* __restrict__ corr) {
    __shared__ float Xs[2][HH][LDS_STRIDE];   // 139264 B (also reduction scratch)

    const int jc  = blockIdx.x;   // j-chunk 0..31
    const int b   = blockIdx.y;   // batch 0..7
    const int tid = threadIdx.x;  // 0..511
    const int J0  = jc * JCHUNK;

    const int w    = tid >> 6;    // wave 0..7 -> i slice [32w, 32w+32)
    const int lane = tid & 63;
    const int lr   = lane >> 3;   // p-group (8 rows  at 8*lr)
    const int lc   = lane & 7;    // q-group (8 cols  at 8*lc)
    const int ib   = 32 * w;

    // --- per-lane tbl entry for i = ib + (lane&31); consumed via readlane.
    float tw0, tw1; int tk0, tk1;
    {
        const double a  = (double)(*angle_p);
        const float  cf = (float)cos(a);
        const float  sf = (float)sin(a);
        const int it = ib + (lane & 31);
        const float gx    = (2.0f * (float)it + 1.0f) / 256.0f - 1.0f; // exact
        const float gridx = cf * gx;
        const float gridz = (-sf) * gx;
        const float ix = ((gridx + 1.0f) * 256.0f - 1.0f) * 0.5f;
        const float t1 = (gridz + 1.0f);        // *D with D=1
        const float iz = (t1 - 1.0f) * 0.5f;
        const float ix0f = floorf(ix), iz0f = floorf(iz);
        const float fx = ix - ix0f,    fz = iz - iz0f;
        const int   ix0 = (int)ix0f,   iz0 = (int)iz0f;
        float wz = 0.0f;
        if (iz0 ==  0) wz += 1.0f - fz;   // dz=0 corner valid (zi=0)
        if (iz0 == -1) wz += fz;          // dz=1 corner valid (zi=0)
        float w0 = (1.0f - fx) * wz;
        float w1 = fx * wz;
        int k0 = ix0, k1 = ix0 + 1;
        if (k0 < 0 || k0 >= WW) { w0 = 0.0f; k0 = 0; }   // zeros padding
        if (k1 < 0 || k1 >= WW) { w1 = 0.0f; k1 = 0; }
        tw0 = w0; tw1 = w1; tk0 = k0; tk1 = k1;
    }

    // --- staging assignment: lanes = channels (bank-bijective ds_writes),
    //     each thread covers 8 float4 i-chunks u = sw + 8v of its channel.
    const int sc   = tid & 63;          // channel
    const int sw   = tid >> 6;          // chunk phase (== wave id)
    const int scol = colw(sc);          // LDS word column for channel sc
    const float* xrow = x + ((size_t)b * CC + sc) * NN;

    float4 sreg[8];

    // prologue: stage j0 into buf0, issue loads for j1
    #pragma unroll
    for (int v = 0; v < 8; ++v)
        sreg[v] = *(const float4*)(xrow + (size_t)J0 * WW + 4 * (sw + 8 * v));
    #pragma unroll
    for (int v = 0; v < 8; ++v) {
        const int u = sw + 8 * v;
        Xs[0][4*u+0][scol] = sreg[v].x;
        Xs[0][4*u+1][scol] = sreg[v].y;
        Xs[0][4*u+2][scol] = sreg[v].z;
        Xs[0][4*u+3][scol] = sreg[v].w;
    }
    #pragma unroll
    for (int v = 0; v < 8; ++v)
        sreg[v] = *(const float4*)(xrow + (size_t)(J0 + 1) * WW + 4 * (sw + 8 * v));
    __syncthreads();

    float4 acc0[8], acc1[8];      // [r]: cols 8lc..+3 / 8lc+4..+7
    #pragma unroll
    for (int r = 0; r < 8; ++r) {
        acc0[r] = make_float4(0.f, 0.f, 0.f, 0.f);
        acc1[r] = make_float4(0.f, 0.f, 0.f, 0.f);
    }

    for (int jj = 0; jj < JCHUNK; ++jj) {
        const int cur = jj & 1;

        // write j(jj+1) into the idle buffer (vmcnt wait; loads issued an
        // entire compute phase ago), then issue loads for j(jj+2)
        if (jj < JCHUNK - 1) {
            #pragma unroll
            for (int v = 0; v < 8; ++v) {
                const int u = sw + 8 * v;
                Xs[cur ^ 1][4*u+0][scol] = sreg[v].x;
                Xs[cur ^ 1][4*u+1][scol] = sreg[v].y;
                Xs[cur ^ 1][4*u+2][scol] = sreg[v].z;
                Xs[cur ^ 1][4*u+3][scol] = sreg[v].w;
            }
        }
        if (jj < JCHUNK - 2) {
            #pragma unroll
            for (int v = 0; v < 8; ++v)
                sreg[v] = *(const float4*)(xrow + (size_t)(J0 + jj + 2) * WW + 4 * (sw + 8 * v));
        }

        // --- compute: 32 i per wave; 6 b128 reads -> 64 FMAs per i
        const float* Xc = &Xs[cur][0][0];
        #pragma unroll 4
        for (int ii = 0; ii < 32; ++ii) {
            const float w0 = rlf(tw0, ii);
            const float w1 = rlf(tw1, ii);
            const int   k0 = __builtin_amdgcn_readlane(tk0, ii);
            const int   k1 = __builtin_amdgcn_readlane(tk1, ii);

            const float* rowP = Xc + (ib + ii) * LDS_STRIDE;
            const float* rowA = Xc + k0 * LDS_STRIDE;
            const float* rowB = Xc + k1 * LDS_STRIDE;

            const float4 xpa = *(const float4*)(rowP + 4 * lr);        // ch 8lr..+3
            const float4 xpb = *(const float4*)(rowP + 4 * lr + 32);   // ch 8lr+4..+7
            const float4 a0  = *(const float4*)(rowA + 4 * lc);
            const float4 a1  = *(const float4*)(rowA + 4 * lc + 32);
            const float4 b0  = *(const float4*)(rowB + 4 * lc);
            const float4 b1  = *(const float4*)(rowB + 4 * lc + 32);

            float4 y0, y1;
            y0.x = fmaf(w1, b0.x, w0 * a0.x);
            y0.y = fmaf(w1, b0.y, w0 * a0.y);
            y0.z = fmaf(w1, b0.z, w0 * a0.z);
            y0.w = fmaf(w1, b0.w, w0 * a0.w);
            y1.x = fmaf(w1, b1.x, w0 * a1.x);
            y1.y = fmaf(w1, b1.y, w0 * a1.y);
            y1.z = fmaf(w1, b1.z, w0 * a1.z);
            y1.w = fmaf(w1, b1.w, w0 * a1.w);

            const float xp[8] = {xpa.x, xpa.y, xpa.z, xpa.w,
                                 xpb.x, xpb.y, xpb.z, xpb.w};
            #pragma unroll
            for (int r = 0; r < 8; ++r) {
                acc0[r].x = fmaf(xp[r], y0.x, acc0[r].x);
                acc0[r].y = fmaf(xp[r], y0.y, acc0[r].y);
                acc0[r].z = fmaf(xp[r], y0.z, acc0[r].z);
                acc0[r].w = fmaf(xp[r], y0.w, acc0[r].w);
                acc1[r].x = fmaf(xp[r], y1.x, acc1[r].x);
                acc1[r].y = fmaf(xp[r], y1.y, acc1[r].y);
                acc1[r].z = fmaf(xp[r], y1.z, acc1[r].z);
                acc1[r].w = fmaf(xp[r], y1.w, acc1[r].w);
            }
        }
        __syncthreads();   // compute(cur) done; writes to cur^1 visible
    }

    // --- cross-wave tree reduction in LDS (reuse Xs: 4 slots x 16 KB)
    float4* S4 = (float4*)&Xs[0][0][0];
    const int idx0 = (8 * lr) * 16 + 2 * lc;   // float4 index; per-r: +16*r

    if (w >= 4) {
        float4* dst = S4 + (size_t)(w - 4) * 1024;
        #pragma unroll
        for (int r = 0; r < 8; ++r) {
            dst[idx0 + 16 * r]     = acc0[r];
            dst[idx0 + 16 * r + 1] = acc1[r];
        }
    }
    __syncthreads();
    if (w < 4) {
        const float4* src = S4 + (size_t)w * 1024;
        #pragma unroll
        for (int r = 0; r < 8; ++r) {
            const float4 u = src[idx0 + 16 * r];
            const float4 v = src[idx0 + 16 * r + 1];
            acc0[r].x += u.x; acc0[r].y += u.y; acc0[r].z += u.z; acc0[r].w += u.w;
            acc1[r].x += v.x; acc1[r].y += v.y; acc1[r].z += v.z; acc1[r].w += v.w;
        }
    }
    __syncthreads();
    if (w == 2 || w == 3) {
        float4* dst = S4 + (size_t)(w - 2) * 1024;
        #pragma unroll
        for (int r = 0; r < 8; ++r) {
            dst[idx0 + 16 * r]     = acc0[r];
            dst[idx0 + 16 * r + 1] = acc1[r];
        }
    }
    __syncthreads();
    if (w < 2) {
        const float4* src = S4 + (size_t)w * 1024;
        #pragma unroll
        for (int r = 0; r < 8; ++r) {
            const float4 u = src[idx0 + 16 * r];
            const float4 v = src[idx0 + 16 * r + 1];
            acc0[r].x += u.x; acc0[r].y += u.y; acc0[r].z += u.z; acc0[r].w += u.w;
            acc1[r].x += v.x; acc1[r].y += v.y; acc1[r].z += v.z; acc1[r].w += v.w;
        }
    }
    __syncthreads();
    if (w == 1) {
        #pragma unroll
        for (int r = 0; r < 8; ++r) {
            S4[idx0 + 16 * r]     = acc0[r];
            S4[idx0 + 16 * r + 1] = acc1[r];
        }
    }
    __syncthreads();
    if (w == 0) {
        #pragma unroll
        for (int r = 0; r < 8; ++r) {
            const float4 u = S4[idx0 + 16 * r];
            const float4 v = S4[idx0 + 16 * r + 1];
            acc0[r].x += u.x; acc0[r].y += u.y; acc0[r].z += u.z; acc0[r].w += u.w;
            acc1[r].x += v.x; acc1[r].y += v.y; acc1[r].z += v.z; acc1[r].w += v.w;
        }
        float* cb = corr + (size_t)b * CC * CC;
        #pragma unroll
        for (int r = 0; r < 8; ++r) {
            const int off = (8 * lr + r) * CC + 8 * lc;
            atomicAdd(&cb[off + 0], acc0[r].x);
            atomicAdd(&cb[off + 1], acc0[r].y);
            atomicAdd(&cb[off + 2], acc0[r].z);
            atomicAdd(&cb[off + 3], acc0[r].w);
            atomicAdd(&cb[off + 4], acc1[r].x);
            atomicAdd(&cb[off + 5], acc1[r].y);
            atomicAdd(&cb[off + 6], acc1[r].z);
            atomicAdd(&cb[off + 7], acc1[r].w);
        }
    }
}

// ---------------------------------------------------------------------------
// Stage 2: softmax over dim=1 (rows i) per column j; store transposed:
//          proT[b][j][i] = softmax_i(corr[b,:,j])[i]
// ---------------------------------------------------------------------------
__global__ void softmax_kernel(const float* __restrict__ corr,
                               float* __restrict__ proT) {
    const int b  = blockIdx.x;
    const int jj = threadIdx.x;   // column j, 0..63
    const float* cb = corr + (size_t)b * CC * CC;
    float v[CC];
    float m = -1e30f;
    #pragma unroll
    for (int i = 0; i < CC; ++i) {
        v[i] = cb[i * CC + jj];
        m = fmaxf(m, v[i]);
    }
    float ssum = 0.0f;
    #pragma unroll
    for (int i = 0; i < CC; ++i) {
        v[i] = expf(v[i] - m);
        ssum += v[i];
    }
    const float inv = 1.0f / ssum;
    float* pb = proT + (size_t)b * CC * CC + (size_t)jj * CC;
    #pragma unroll
    for (int i = 0; i < CC; ++i) pb[i] = v[i] * inv;
}

// ---------------------------------------------------------------------------
// Stage 3: out[b,p,n] = sum_q pro[b,p,q] * x[b,q,n]
// One block per (b, 256-col chunk). 512 threads = 8 waves; each wave owns
// 8 p-rows. Plain float4 stores (NT stores showed 6x WRITE_SIZE
// amplification). Statically-indexed prefetch pipeline (rule #20 via unroll 4).
// ---------------------------------------------------------------------------
__global__ __launch_bounds__(512, 4)
void apply_kernel(const float* __restrict__ x, const float* __restrict__ proT,
                  float* __restrict__ out) {
    __shared__ float P[CC * CC];   // P[q*64 + p] = pro[p][q]
    const int b   = blockIdx.y;
    const int n0  = blockIdx.x * 256;
    const int tid = threadIdx.x;
    for (int t = tid; t < CC * CC; t += 512)
        P[t] = proT[(size_t)b * CC * CC + t];
    __syncthreads();

    const int lane = tid & 63;
    const int w    = tid >> 6;     // wave index == p-group (8 p's each)
    const float* xb = x + (size_t)b * CC * NN + n0 + 4 * lane;

    float4 acc[8];
    #pragma unroll
    for (int r = 0; r < 8; ++r) acc[r] = make_float4(0.f, 0.f, 0.f, 0.f);

    // 4-deep prefetch pipeline: 4 KB in flight per wave
    float4 buf[4];
    #pragma unroll
    for (int u = 0; u < 4; ++u) buf[u] = *(const float4*)(xb + (size_t)u * NN);

    #pragma unroll 4
    for (int q = 0; q < CC; ++q) {
        const float4 xv = buf[q & 3];
        if (q + 4 < CC) buf[q & 3] = *(const float4*)(xb + (size_t)(q + 4) * NN);

        const float4 pa = *(const float4*)&P[q * CC + 8 * w];
        const float4 pb = *(const float4*)&P[q * CC + 8 * w + 4];
        const float pv[8] = {pa.x, pa.y, pa.z, pa.w, pb.x, pb.y, pb.z, pb.w};
        #pragma unroll
        for (int r = 0; r < 8; ++r) {
            acc[r].x = fmaf(pv[r], xv.x, acc[r].x);
            acc[r].y = fmaf(pv[r], xv.y, acc[r].y);
            acc[r].z = fmaf(pv[r], xv.z, acc[r].z);
            acc[r].w = fmaf(pv[r], xv.w, acc[r].w);
        }
    }

    float* ob = out + (size_t)b * CC * NN + n0 + 4 * lane;
    #pragma unroll
    for (int r = 0; r < 8; ++r) {
        *(float4*)(ob + (size_t)(8 * w + r) * NN) = acc[r];
    }
}

// ---------------------------------------------------------------------------
extern "C" void kernel_launch(void* const* d_in, const int* in_sizes, int n_in,
                              void* d_out, int out_size, void* d_ws, size_t ws_size,
                              hipStream_t stream) {
    const float* x     = (const float*)d_in[0];
    const int*   angle = (const int*)d_in[1];
    float*       out   = (float*)d_out;

    float* corr = (float*)d_ws;                  // [8][64][64]
    float* proT = corr + (size_t)BB * CC * CC;   // [8][64(j)][64(i)]

    (void)hipMemsetAsync(d_ws, 0, (size_t)BB * CC * CC * sizeof(float), stream);

    corr_kernel<<<dim3(HH / JCHUNK, BB), 512, 0, stream>>>(x, angle, corr);
    softmax_kernel<<<dim3(BB), dim3(CC), 0, stream>>>(corr, proT);
    apply_kernel<<<dim3(NN / 256, BB), 512, 0, stream>>>(x, proT, out);
}